// Round 24
// baseline (522.680 us; speedup 1.0000x reference)
//
#include <hip/hip_runtime.h>
#include <hip/hip_bf16.h>

typedef __hip_bfloat16 bf16;
typedef __attribute__((ext_vector_type(8))) short s16x8;
typedef __attribute__((ext_vector_type(4))) short s16x4;
typedef __attribute__((ext_vector_type(4))) float f32x4;

// Problem constants
#define BATCH 8
#define NH 8
#define NTOK 3137         // H*W+1
#define HD 96             // head dim
#define HH 56
#define WW 56
#define NKEY 785          // 28*28+1
#define DIMC 768
#define DIM3 2304
#define MROWS (BATCH * NTOK)   // 25096

__device__ __forceinline__ float b2f(bf16 x) { return __bfloat162float(x); }
__device__ __forceinline__ bf16 f2b(float x) { return __float2bfloat16(x); }
__device__ __forceinline__ float s2f(short s) {
  return __uint_as_float(((uint32_t)(uint16_t)s) << 16);
}
__device__ __forceinline__ short f2bs(float x) {
  bf16 h = __float2bfloat16(x);
  short s; __builtin_memcpy(&s, &h, 2); return s;
}
__device__ __forceinline__ void gload_lds16(const void* g, void* l) {
  __builtin_amdgcn_global_load_lds(
      (const __attribute__((address_space(1))) void*)g,
      (__attribute__((address_space(3))) void*)l, 16, 0, 0);
}
// Bijective XCD-chunked swizzle (m204): contiguous work ranges per XCD.
__device__ __forceinline__ int xcd_swz(int bid, int nwg) {
  int q = nwg >> 3, r = nwg & 7;
  int xcd = bid & 7, idx = bid >> 3;
  return (xcd < r ? xcd * (q + 1) : r * (q + 1) + (xcd - r) * q) + idx;
}

// ---------------- Kernel 0: fused converts (W-transpose | Brel | X) ----------------
__global__ __launch_bounds__(256) void k_cvtAll(
    const float* __restrict__ X, bf16* __restrict__ Xb, int n4,
    const float* __restrict__ W, bf16* __restrict__ WbT,
    const float* __restrict__ relHt, const float* __restrict__ relWt,
    bf16* __restrict__ Brel) {
  __shared__ float T[64][65];
  const int bid = blockIdx.x;
  const int tid = threadIdx.x;
  if (bid < 432) {            // ---- W [768][2304] -> W^T [2304][768] bf16 ----
    const int n0 = (bid % 36) * 64;
    const int k0 = (bid / 36) * 64;
#pragma unroll
    for (int i = 0; i < 16; i++) {
      int e = tid + i * 256;
      int r = e >> 6, c = e & 63;
      T[r][c] = W[(size_t)(k0 + r) * DIM3 + n0 + c];
    }
    __syncthreads();
#pragma unroll
    for (int i = 0; i < 16; i++) {
      int e = tid + i * 256;
      int r = e >> 6, c = e & 63;
      WbT[(size_t)(n0 + r) * DIMC + k0 + c] = f2b(T[c][r]);
    }
  } else if (bid < 453) {     // ---- Brel [224][96] bf16 ----
    int i = (bid - 432) * 256 + tid;
    if (i < 5376) {
      int elem = i * 4;
      int row = elem / HD, c = elem % HD;
      float4 v = {0.f, 0.f, 0.f, 0.f};
      if (row < 111) v = *(const float4*)(relHt + (size_t)row * HD + c);
      else if (row >= 112 && row < 223) v = *(const float4*)(relWt + (size_t)(row - 112) * HD + c);
      short4 o;
      o.x = f2bs(v.x); o.y = f2bs(v.y); o.z = f2bs(v.z); o.w = f2bs(v.w);
      *(short4*)((short*)Brel + elem) = o;
    }
  } else {                    // ---- X fp32 -> bf16 ----
    for (int i = (bid - 453) * 256 + tid; i < n4; i += (2501 - 453) * 256) {
      float4 v = reinterpret_cast<const float4*>(X)[i];
      ushort4 o;
      o.x = (unsigned short)f2bs(v.x); o.y = (unsigned short)f2bs(v.y);
      o.z = (unsigned short)f2bs(v.z); o.w = (unsigned short)f2bs(v.w);
      reinterpret_cast<ushort4*>(Xb)[i] = o;
    }
  }
}

// ---------------- Kernel 1: QKV projection, bf16 MFMA (R20-proven) ----------------
#define QKV_NBX 18
#define QKV_NBY 197
#define QKV_NWG (QKV_NBX * QKV_NBY)   // 3546

__global__ __launch_bounds__(256, 4) void k_qkv_mfma(
    const bf16* __restrict__ Xb, const bf16* __restrict__ WbT,
    const float* __restrict__ bias,
    bf16* __restrict__ Q, bf16* __restrict__ K, bf16* __restrict__ V) {
  __shared__ __align__(16) short LB[17408];   // 34816 B
  const int tid = threadIdx.x;
  const int wid = tid >> 6, lane = tid & 63;
  const int g = lane >> 4, kl = lane & 15;
  const int wm = wid >> 1, wn = wid & 1;
  const int lin = xcd_swz(blockIdx.x, QKV_NWG);
  const int row0 = (lin / QKV_NBX) * 128;
  const int col0 = (lin % QKV_NBX) * 128;

  auto stage = [&](int k0, int buf) {
#pragma unroll
    for (int r = 0; r < 2; r++) {
      int slotb = r * 256 + wid * 64;         // wave-uniform LDS base
      int slot = slotb + lane;
      int sg = slot >> 7, sm = slot & 127;
      int mm = row0 + sm; if (mm > MROWS - 1) mm = MROWS - 1;
      gload_lds16(Xb + (size_t)mm * DIMC + k0 + sg * 8, &LB[buf * 4096 + (slotb << 3)]);
      gload_lds16(WbT + (size_t)(col0 + sm) * DIMC + k0 + sg * 8,
                  &LB[8192 + buf * 4096 + (slotb << 3)]);
    }
  };

  f32x4 acc[4][4] = {};

  stage(0, 0);
  __syncthreads();

  for (int it = 0; it < 24; it++) {
    const int buf = it & 1;
    if (it < 23) stage((it + 1) * 32, buf ^ 1);

    s16x8 af[4], bf[4];
#pragma unroll
    for (int i = 0; i < 4; i++)
      af[i] = *(const s16x8*)&LB[buf * 4096 + (((g << 7) + wm * 64 + i * 16 + kl) << 3)];
#pragma unroll
    for (int j = 0; j < 4; j++)
      bf[j] = *(const s16x8*)&LB[8192 + buf * 4096 + (((g << 7) + wn * 64 + j * 16 + kl) << 3)];
    __builtin_amdgcn_s_setprio(1);
#pragma unroll
    for (int i = 0; i < 4; i++)
#pragma unroll
      for (int j = 0; j < 4; j++)
        acc[i][j] = __builtin_amdgcn_mfma_f32_16x16x32_bf16(af[i], bf[j], acc[i][j], 0, 0, 0);
    __builtin_amdgcn_s_setprio(0);
    __syncthreads();
  }

  // ---- epilogue: bias + LDS transpose + vectorized coalesced writes ----
#pragma unroll
  for (int i = 0; i < 4; i++)
#pragma unroll
    for (int j = 0; j < 4; j++) {
      int n = wn * 64 + j * 16 + kl;
      float bv = bias[col0 + n];
#pragma unroll
      for (int r = 0; r < 4; r++) {
        int m = wm * 64 + i * 16 + g * 4 + r;
        LB[m * 136 + n] = f2bs(acc[i][j][r] + bv);
      }
    }
  __syncthreads();
#pragma unroll
  for (int cc8 = 0; cc8 < 8; cc8++) {
    int ch = tid + cc8 * 256;
    int m = ch >> 4, cc = ch & 15;
    int M = row0 + m;
    if (M < MROWS) {
      int ncol = col0 + cc * 8;
      int s = ncol / DIMC, rr = ncol % DIMC;
      int h = rr / HD, c = rr % HD;
      int b = M / NTOK, nt = M % NTOK;
      bf16* dst = (s == 0) ? Q : (s == 1) ? K : V;
      *(uint4*)(dst + (((size_t)b * NH + h) * NTOK + nt) * HD + c) =
          *(const uint4*)&LB[m * 136 + cc * 8];
    }
  }
}

// ---------------- Kernel 2a: fused poolK+poolV (stride 2) ----------------
__global__ __launch_bounds__(256) void k_poolKV(
    const bf16* __restrict__ rawK, const bf16* __restrict__ rawV,
    const float* __restrict__ wk, const float* __restrict__ wv,
    const float* __restrict__ gk, const float* __restrict__ bk,
    const float* __restrict__ gv, const float* __restrict__ bv,
    bf16* __restrict__ outK, bf16* __restrict__ outV) {
  const int ntok = 785, ngrp = 197, nb = 64 * ngrp;
  const bool isV = blockIdx.x >= nb;
  const int bid = xcd_swz(isV ? blockIdx.x - nb : blockIdx.x, nb);
  const bf16* raw = isV ? rawV : rawK;
  const float* wgt = isV ? wv : wk;
  const float* gam = isV ? gv : gk;
  const float* bet = isV ? bv : bk;
  bf16* out = isV ? outV : outK;
  const int grp = bid % ngrp;
  const int bh = bid / ngrp;
  const int wid = threadIdx.x >> 6, lane = threadIdx.x & 63;
  const int t = grp * 4 + wid;
  if (t >= ntok) return;
  const bf16* src = raw + (size_t)bh * NTOK * HD;
  const int c2 = lane * 2;

  float v0 = 0.f, v1 = 0.f;
  if (lane < 48) {
    if (t == 0) {
      ushort2 u = *(const ushort2*)(src + c2);
      v0 = s2f((short)u.x); v1 = s2f((short)u.y);
    } else {
      int oy = (t - 1) / 28, ox = (t - 1) % 28;
#pragma unroll
      for (int dy = 0; dy < 3; dy++) {
        int iy = oy * 2 + dy - 1;
        if (iy < 0 || iy >= HH) continue;
#pragma unroll
        for (int dx = 0; dx < 3; dx++) {
          int ix = ox * 2 + dx - 1;
          if (ix < 0 || ix >= WW) continue;
          ushort2 u = *(const ushort2*)(src + (size_t)(1 + iy * WW + ix) * HD + c2);
          float2 w = *(const float2*)(wgt + (dy * 3 + dx) * HD + c2);
          v0 += s2f((short)u.x) * w.x;
          v1 += s2f((short)u.y) * w.y;
        }
      }
    }
  }
  float s = v0 + v1;
  float s2 = v0 * v0 + v1 * v1;
#pragma unroll
  for (int o = 32; o > 0; o >>= 1) {
    s += __shfl_xor(s, o);
    s2 += __shfl_xor(s2, o);
  }
  float mean = s * (1.f / 96.f);
  float var = s2 * (1.f / 96.f) - mean * mean;
  float rstd = rsqrtf(var + 1e-5f);

  if (lane < 48) {
    float2 gm = *(const float2*)(gam + c2);
    float2 bt = *(const float2*)(bet + c2);
    ushort2 o2;
    o2.x = (unsigned short)f2bs((v0 - mean) * rstd * gm.x + bt.x);
    o2.y = (unsigned short)f2bs((v1 - mean) * rstd * gm.y + bt.y);
    *(ushort2*)(out + ((size_t)bh * ntok + t) * HD + c2) = o2;
  }
}

// ---------------- Kernel 2b: poolQ (stride 1) ----------------
__global__ __launch_bounds__(256) void k_poolQ(
    const bf16* __restrict__ raw, const float* __restrict__ wgt,
    const float* __restrict__ gam, const float* __restrict__ bet,
    bf16* __restrict__ out) {
  const int ntok = NTOK, ngrp = 785;
  const int bid = xcd_swz(blockIdx.x, 64 * ngrp);
  const int grp = bid % ngrp;
  const int bh = bid / ngrp;
  const int wid = threadIdx.x >> 6, lane = threadIdx.x & 63;
  const int t = grp * 4 + wid;
  if (t >= ntok) return;
  const bf16* src = raw + (size_t)bh * NTOK * HD;
  const int c2 = lane * 2;

  float v0 = 0.f, v1 = 0.f;
  if (lane < 48) {
    if (t == 0) {
      ushort2 u = *(const ushort2*)(src + c2);
      v0 = s2f((short)u.x); v1 = s2f((short)u.y);
    } else {
      int oy = (t - 1) / WW, ox = (t - 1) % WW;
#pragma unroll
      for (int dy = 0; dy < 3; dy++) {
        int iy = oy + dy - 1;
        if (iy < 0 || iy >= HH) continue;
#pragma unroll
        for (int dx = 0; dx < 3; dx++) {
          int ix = ox + dx - 1;
          if (ix < 0 || ix >= WW) continue;
          ushort2 u = *(const ushort2*)(src + (size_t)(1 + iy * WW + ix) * HD + c2);
          float2 w = *(const float2*)(wgt + (dy * 3 + dx) * HD + c2);
          v0 += s2f((short)u.x) * w.x;
          v1 += s2f((short)u.y) * w.y;
        }
      }
    }
  }
  float s = v0 + v1;
  float s2 = v0 * v0 + v1 * v1;
#pragma unroll
  for (int o = 32; o > 0; o >>= 1) {
    s += __shfl_xor(s, o);
    s2 += __shfl_xor(s2, o);
  }
  float mean = s * (1.f / 96.f);
  float var = s2 * (1.f / 96.f) - mean * mean;
  float rstd = rsqrtf(var + 1e-5f);

  if (lane < 48) {
    float2 gm = *(const float2*)(gam + c2);
    float2 bt = *(const float2*)(bet + c2);
    ushort2 o2;
    o2.x = (unsigned short)f2bs((v0 - mean) * rstd * gm.x + bt.x);
    o2.y = (unsigned short)f2bs((v1 - mean) * rstd * gm.y + bt.y);
    *(ushort2*)(out + ((size_t)bh * ntok + t) * HD + c2) = o2;
  }
}

// ---------------- Kernel 3: MFMA flash attention v9 (v7 + T14 async-STAGE split) ----------------
#define KS_OFF 0
#define VS_OFF 8192
#define RHT_OFF 14528
#define RWT_OFF 16432
#define PS_OFF 18336

__global__ __launch_bounds__(256, 4) void k_attn(
    const bf16* __restrict__ Qp, const bf16* __restrict__ Kp,
    const bf16* __restrict__ Vp, const bf16* __restrict__ BrelG,
    float* __restrict__ out) {
  __shared__ __align__(16) short LB[20384];

  const int bid = blockIdx.x;
  const int swz = (bid & 7) * 400 + (bid >> 3);
  const int bh = swz / 50, qt = swz % 50;
  const int qbase = qt * 64;
  const int tid = threadIdx.x, wid = tid >> 6, lane = tid & 63;
  const int g = lane >> 4, kl = lane & 15;
  const int bb = bh >> 3, hh = bh & 7;
  const float scale = 0.10206207261596575f;

  const bf16* Qbh = Qp + (size_t)bh * NTOK * HD;
  const bf16* Kbh = Kp + (size_t)bh * NKEY * HD;
  const bf16* Vbh = Vp + (size_t)bh * NKEY * HD;

  // ---- Q fragments direct from global ----
  s16x8 qf[3];
  {
    int qg = qbase + wid * 16 + kl; if (qg > NTOK - 1) qg = NTOK - 1;
    const bf16* qptr = Qbh + (size_t)qg * HD;
#pragma unroll
    for (int f = 0; f < 3; f++)
      qf[f] = *(const s16x8*)(qptr + f * 32 + g * 8);
  }

  // ---- fused rel tables: S = Q(64x96) · Brel^T(224x96), gather -> RHT/RWT ----
  {
    short* SfH = &LB[0];          // [64][112]
    short* SfW = &LB[7168];       // [64][112]  (non-overlapping, dead until stage)
    f32x4 accH[7], accW[7];
#pragma unroll
    for (int cf = 0; cf < 7; cf++) {
      accH[cf] = (f32x4){0.f, 0.f, 0.f, 0.f};
      accW[cf] = (f32x4){0.f, 0.f, 0.f, 0.f};
    }
#pragma unroll
    for (int cf = 0; cf < 7; cf++) {
#pragma unroll
      for (int kb = 0; kb < 3; kb++) {
        s16x8 bh_ = *(const s16x8*)((const short*)BrelG + (cf * 16 + kl) * 96 + kb * 32 + g * 8);
        s16x8 bw_ = *(const s16x8*)((const short*)BrelG + (112 + cf * 16 + kl) * 96 + kb * 32 + g * 8);
        accH[cf] = __builtin_amdgcn_mfma_f32_16x16x32_bf16(qf[kb], bh_, accH[cf], 0, 0, 0);
        accW[cf] = __builtin_amdgcn_mfma_f32_16x16x32_bf16(qf[kb], bw_, accW[cf], 0, 0, 0);
      }
    }
#pragma unroll
    for (int cf = 0; cf < 7; cf++)
#pragma unroll
      for (int r = 0; r < 4; r++) {
        int row = wid * 16 + g * 4 + r;
        SfH[row * 112 + cf * 16 + kl] = f2bs(accH[cf][r]);
        SfW[row * 112 + cf * 16 + kl] = f2bs(accW[cf][r]);
      }
    __syncthreads();
    for (int i = tid; i < 1792; i += 256) {
      int ql = i / 28, j = i % 28;
      int qg = qbase + ql; if (qg > NTOK - 1) qg = NTOK - 1;
      int qy, qx;
      if (qg < 1) { qy = 0; qx = 0; } else { qy = (qg - 1) / WW; qx = (qg - 1) % WW; }
      int ih = qy - 2 * j + 54; ih = ih < 0 ? 0 : (ih > 110 ? 110 : ih);
      int iw = qx - 2 * j + 54; iw = iw < 0 ? 0 : (iw > 110 ? 110 : iw);
      LB[RHT_OFF + j * 68 + ql] = SfH[ql * 112 + ih];
      LB[RWT_OFF + j * 68 + ql] = SfW[ql * 112 + iw];
    }
    __syncthreads();
  }

  // ---- all-ones bf16 B-fragment for the row-sum MFMA ----
  s16x8 ones;
#pragma unroll
  for (int e = 0; e < 8; e++) ones[e] = (short)0x3F80;

  // ---- staging descriptors (chunk0: all threads; chunk1: tid<128) ----
  int kd0, vd0, go0, cs0, kd1, vd1, go1, cs1;
  {
    int kk = tid / 12, ch = tid % 12;
    kd0 = kk * 128 + ((ch ^ (kk & 7)) << 3);
    vd0 = (ch >> 1) * 528 + kk * 16 + ((ch & 1) << 3);
    go0 = kk * 96 + ch * 8;
    cs0 = (kk > 16) ? (kk - 16) * 96 : 0;
    int idx = 256 + tid;
    kk = idx / 12; ch = idx % 12;
    kd1 = kk * 128 + ((ch ^ (kk & 7)) << 3);
    vd1 = (ch >> 1) * 528 + kk * 16 + ((ch & 1) << 3);
    go1 = kk * 96 + ch * 8;
    cs1 = (kk > 16) ? (kk - 16) * 96 : 0;
  }

  // prologue: full stage of tile 0 into buf 0
  {
    uint4 ku = *(const uint4*)((const short*)Kbh + go0);
    uint4 vu = *(const uint4*)((const short*)Vbh + go0);
    *(uint4*)&LB[KS_OFF + kd0] = ku;
    *(uint4*)&LB[VS_OFF + vd0] = vu;
    go0 += 32 * 96;
    if (tid < 128) {
      uint4 ku1 = *(const uint4*)((const short*)Kbh + go1);
      uint4 vu1 = *(const uint4*)((const short*)Vbh + go1);
      *(uint4*)&LB[KS_OFF + kd1] = ku1;
      *(uint4*)&LB[VS_OFF + vd1] = vu1;
      go1 += 32 * 96;
    }
  }
  __syncthreads();

  f32x4 o[7];   // o[0..5]: output cblks; o[6]: row-sum (softmax denominator)
#pragma unroll
  for (int cb = 0; cb < 7; cb++) o[cb] = (f32x4){0.f, 0.f, 0.f, 0.f};

  // incremental rel indices (k0g = t*32+kl; e = k0g-1)
  int kx0 = kl - 1;
  int ky0 = 0;
  int kx1 = (15 + kl) % 28;
  int ky1 = (15 + kl) / 28;
  const int qlb = wid * 16 + g * 4;

  for (int t = 0; t < 25; t++) {
    const int buf = t & 1;

    // ---- T14 LOAD phase: issue next-tile global loads (writes deferred) ----
    uint4 ku, vu, ku1, vu1;
    if (t < 24) {
      int a0 = go0 - ((t == 23) ? cs0 : 0);   // staged tile index = t+1
      ku = *(const uint4*)((const short*)Kbh + a0);
      vu = *(const uint4*)((const short*)Vbh + a0);
      go0 += 32 * 96;
      if (tid < 128) {
        int a1 = go1 - ((t == 23) ? cs1 : 0);
        ku1 = *(const uint4*)((const short*)Kbh + a1);
        vu1 = *(const uint4*)((const short*)Vbh + a1);
        go1 += 32 * 96;
      }
    }

    // ---- QK^T ----
    const short* ksb = &LB[KS_OFF + buf * 4096];
    f32x4 s0 = (f32x4){0.f, 0.f, 0.f, 0.f};
    f32x4 s1 = (f32x4){0.f, 0.f, 0.f, 0.f};
    __builtin_amdgcn_s_setprio(1);
#pragma unroll
    for (int f = 0; f < 3; f++) {
      int ch = f * 4 + g;
      int r0 = kl, r1 = 16 + kl;
      s16x8 kf0 = *(const s16x8*)&ksb[r0 * 128 + ((ch ^ (r0 & 7)) << 3)];
      s16x8 kf1 = *(const s16x8*)&ksb[r1 * 128 + ((ch ^ (r1 & 7)) << 3)];
      s0 = __builtin_amdgcn_mfma_f32_16x16x32_bf16(qf[f], kf0, s0, 0, 0, 0);
      s1 = __builtin_amdgcn_mfma_f32_16x16x32_bf16(qf[f], kf1, s1, 0, 0, 0);
    }
    __builtin_amdgcn_s_setprio(0);

    // ---- rel gather: 4x ds_read_b64 from transposed tables ----
    const int k0g = t * 32 + kl;
    const int k1g = k0g + 16;
    int kxu0 = kx0 < 0 ? 0 : kx0;
    int kyu1 = ky1 > 27 ? 27 : ky1;
    s16x4 rh0 = *(const s16x4*)&LB[RHT_OFF + ky0 * 68 + qlb];
    s16x4 rw0 = *(const s16x4*)&LB[RWT_OFF + kxu0 * 68 + qlb];
    s16x4 rh1 = *(const s16x4*)&LB[RHT_OFF + kyu1 * 68 + qlb];
    s16x4 rw1 = *(const s16x4*)&LB[RWT_OFF + kx1 * 68 + qlb];

    // ---- logits + NO-MAX softmax: p = exp(lg) directly (bounded logits) ----
    float p0[4], p1[4];
#pragma unroll
    for (int r = 0; r < 4; r++) {
      int qg = qbase + qlb + r;
      float rel0 = (qg > 0 && k0g > 0) ? s2f(rh0[r]) + s2f(rw0[r]) : 0.f;
      float rel1 = (qg > 0) ? s2f(rh1[r]) + s2f(rw1[r]) : 0.f;
      float lg0 = s0[r] * scale + rel0;
      float lg1 = (k1g < NKEY) ? (s1[r] * scale + rel1) : -1e30f;
      p0[r] = __expf(lg0);
      p1[r] = __expf(lg1);        // expf(-1e30) underflows to 0: masked
    }
    kx0 += 4; ky0 += 1; if (kx0 >= 28) { kx0 -= 28; ky0 += 1; }
    kx1 += 4; ky1 += 1; if (kx1 >= 28) { kx1 -= 28; ky1 += 1; }

    // ---- P^T -> LDS [32k][16q]: 2x ds_write_b64; A-frag via 2x tr-read ----
    short* pw = &LB[PS_OFF + wid * 512];
    s16x4 pk0, pk1;
#pragma unroll
    for (int r = 0; r < 4; r++) { pk0[r] = f2bs(p0[r]); pk1[r] = f2bs(p1[r]); }
    *(s16x4*)(pw + kl * 16 + g * 4) = pk0;
    *(s16x4*)(pw + (16 + kl) * 16 + g * 4) = pk1;
    __builtin_amdgcn_sched_barrier(0);
    uint32_t pbase = (uint32_t)(size_t)pw + (uint32_t)(g * 256 + kl * 8);
    s16x4 pt0, pt1;
    asm volatile("ds_read_b64_tr_b16 %0, %1" : "=v"(pt0) : "v"(pbase));
    asm volatile("ds_read_b64_tr_b16 %0, %1 offset:128" : "=v"(pt1) : "v"(pbase));

    // ---- V tr-reads ----
    uint32_t vbase = (uint32_t)(size_t)&LB[VS_OFF + buf * 3168] + (uint32_t)(g * 256 + kl * 8);
    s16x4 tv[12];
#pragma unroll
    for (int cb = 0; cb < 6; cb++) {
      uint32_t va = vbase + cb * 1056;
      asm volatile("ds_read_b64_tr_b16 %0, %1" : "=v"(tv[2 * cb]) : "v"(va));
      asm volatile("ds_read_b64_tr_b16 %0, %1 offset:128" : "=v"(tv[2 * cb + 1]) : "v"(va));
    }
    asm volatile("s_waitcnt lgkmcnt(0)" ::: "memory");
    __builtin_amdgcn_sched_barrier(0);

    s16x8 pa = __builtin_shufflevector(pt0, pt1, 0, 1, 2, 3, 4, 5, 6, 7);
    __builtin_amdgcn_s_setprio(1);
    o[6] = __builtin_amdgcn_mfma_f32_16x16x32_bf16(pa, ones, o[6], 0, 0, 0);
#pragma unroll
    for (int cb = 0; cb < 6; cb++) {
      s16x8 vf = __builtin_shufflevector(tv[2 * cb], tv[2 * cb + 1], 0, 1, 2, 3, 4, 5, 6, 7);
      o[cb] = __builtin_amdgcn_mfma_f32_16x16x32_bf16(pa, vf, o[cb], 0, 0, 0);
    }
    __builtin_amdgcn_s_setprio(0);

    // ---- T14 WRITE phase: deferred LDS writes into buf^1 (HBM latency hidden) ----
    if (t < 24) {
      short* ksb_n = &LB[KS_OFF + (buf ^ 1) * 4096];
      short* vsb_n = &LB[VS_OFF + (buf ^ 1) * 3168];
      *(uint4*)&ksb_n[kd0] = ku;
      *(uint4*)&vsb_n[vd0] = vu;
      if (tid < 128) {
        *(uint4*)&ksb_n[kd1] = ku1;
        *(uint4*)&vsb_n[vd1] = vu1;
      }
    }
    __syncthreads();
  }

  // ---- epilogue: normalize + residual + transposed store ----
  float inv[4];
#pragma unroll
  for (int r = 0; r < 4; r++) inv[r] = 1.f / o[6][r];
#pragma unroll
  for (int cb = 0; cb < 6; cb++) {
#pragma unroll
    for (int r = 0; r < 4; r++) {
      int ql = qlb + r;
      int qg = qbase + ql;
      if (qg < NTOK) {
        int c = cb * 16 + kl;
        float val = o[cb][r] * inv[r] + b2f(Qbh[(size_t)qg * HD + c]);
        out[((size_t)bb * NTOK + qg) * 768 + hh * 96 + c] = val;
      }
    }
  }
}

// ---------------- launch ----------------
extern "C" void kernel_launch(void* const* d_in, const int* in_sizes, int n_in,
                              void* d_out, int out_size, void* d_ws, size_t ws_size,
                              hipStream_t stream) {
  const float* x = (const float*)d_in[0];
  const float* qkv_w = (const float*)d_in[1];
  const float* qkv_b = (const float*)d_in[2];
  const float* pqw = (const float*)d_in[3];
  const float* pkw = (const float*)d_in[4];
  const float* pvw = (const float*)d_in[5];
  const float* nqg = (const float*)d_in[6];
  const float* nqb = (const float*)d_in[7];
  const float* nkg = (const float*)d_in[8];
  const float* nkb = (const float*)d_in[9];
  const float* nvg = (const float*)d_in[10];
  const float* nvb = (const float*)d_in[11];
  const float* relH = (const float*)d_in[12];
  const float* relW = (const float*)d_in[13];

  const size_t SZQ = (size_t)MROWS * DIMC;             // 19,273,728 elems
  const size_t SZK = (size_t)BATCH * NH * NKEY * HD;   //  4,823,040 elems

  bf16* ws = (bf16*)d_ws;
  bf16* Xb   = (bf16*)d_out;
  bf16* rawV = (bf16*)d_out + SZQ;
  bf16* rawQ = ws;
  bf16* rawK = ws + SZQ;
  bf16* WbT  = ws + 2 * SZQ;
  bf16* poolK = ws + 2 * SZQ;
  bf16* poolV = poolK + SZK;
  bf16* poolQ = rawK;                      // aliases rawK (dead after poolKV)
  bf16* Brel = ws + 2 * SZQ + 2 * SZK;     // outside all written regions
  float* out = (float*)d_out;

  k_cvtAll<<<2501, 256, 0, stream>>>(x, Xb, (int)(SZQ / 4), qkv_w, WbT,
                                     relH, relW, Brel);

  k_qkv_mfma<<<QKV_NWG, 256, 0, stream>>>(Xb, WbT, qkv_b, rawQ, rawK, rawV);

  k_poolKV<<<2 * 64 * 197, 256, 0, stream>>>(rawK, rawV, pkw, pvw,
                                             nkg, nkb, nvg, nvb, poolK, poolV);
  k_poolQ<<<64 * 785, 256, 0, stream>>>(rawQ, pqw, nqg, nqb, poolQ);

  k_attn<<<64 * 50, 256, 0, stream>>>(poolQ, poolK, poolV, Brel, out);
}

// Round 25
// 510.399 us; speedup vs baseline: 1.0241x; 1.0241x over previous
//
#include <hip/hip_runtime.h>
#include <hip/hip_bf16.h>

typedef __hip_bfloat16 bf16;
typedef __attribute__((ext_vector_type(8))) short s16x8;
typedef __attribute__((ext_vector_type(4))) short s16x4;
typedef __attribute__((ext_vector_type(4))) float f32x4;

// Problem constants
#define BATCH 8
#define NH 8
#define NTOK 3137         // H*W+1
#define HD 96             // head dim
#define HH 56
#define WW 56
#define NKEY 785          // 28*28+1
#define DIMC 768
#define DIM3 2304
#define MROWS (BATCH * NTOK)   // 25096

__device__ __forceinline__ float b2f(bf16 x) { return __bfloat162float(x); }
__device__ __forceinline__ bf16 f2b(float x) { return __float2bfloat16(x); }
__device__ __forceinline__ float s2f(short s) {
  return __uint_as_float(((uint32_t)(uint16_t)s) << 16);
}
__device__ __forceinline__ short f2bs(float x) {
  bf16 h = __float2bfloat16(x);
  short s; __builtin_memcpy(&s, &h, 2); return s;
}
__device__ __forceinline__ void gload_lds16(const void* g, void* l) {
  __builtin_amdgcn_global_load_lds(
      (const __attribute__((address_space(1))) void*)g,
      (__attribute__((address_space(3))) void*)l, 16, 0, 0);
}
// Bijective XCD-chunked swizzle (m204): contiguous work ranges per XCD.
__device__ __forceinline__ int xcd_swz(int bid, int nwg) {
  int q = nwg >> 3, r = nwg & 7;
  int xcd = bid & 7, idx = bid >> 3;
  return (xcd < r ? xcd * (q + 1) : r * (q + 1) + (xcd - r) * q) + idx;
}

// ---------------- Kernel 0: fused converts (W-transpose | Brel | X) ----------------
__global__ __launch_bounds__(256) void k_cvtAll(
    const float* __restrict__ X, bf16* __restrict__ Xb, int n4,
    const float* __restrict__ W, bf16* __restrict__ WbT,
    const float* __restrict__ relHt, const float* __restrict__ relWt,
    bf16* __restrict__ Brel) {
  __shared__ float T[64][65];
  const int bid = blockIdx.x;
  const int tid = threadIdx.x;
  if (bid < 432) {            // ---- W [768][2304] -> W^T [2304][768] bf16 ----
    const int n0 = (bid % 36) * 64;
    const int k0 = (bid / 36) * 64;
#pragma unroll
    for (int i = 0; i < 16; i++) {
      int e = tid + i * 256;
      int r = e >> 6, c = e & 63;
      T[r][c] = W[(size_t)(k0 + r) * DIM3 + n0 + c];
    }
    __syncthreads();
#pragma unroll
    for (int i = 0; i < 16; i++) {
      int e = tid + i * 256;
      int r = e >> 6, c = e & 63;
      WbT[(size_t)(n0 + r) * DIMC + k0 + c] = f2b(T[c][r]);
    }
  } else if (bid < 453) {     // ---- Brel [224][96] bf16 ----
    int i = (bid - 432) * 256 + tid;
    if (i < 5376) {
      int elem = i * 4;
      int row = elem / HD, c = elem % HD;
      float4 v = {0.f, 0.f, 0.f, 0.f};
      if (row < 111) v = *(const float4*)(relHt + (size_t)row * HD + c);
      else if (row >= 112 && row < 223) v = *(const float4*)(relWt + (size_t)(row - 112) * HD + c);
      short4 o;
      o.x = f2bs(v.x); o.y = f2bs(v.y); o.z = f2bs(v.z); o.w = f2bs(v.w);
      *(short4*)((short*)Brel + elem) = o;
    }
  } else {                    // ---- X fp32 -> bf16 ----
    for (int i = (bid - 453) * 256 + tid; i < n4; i += (2501 - 453) * 256) {
      float4 v = reinterpret_cast<const float4*>(X)[i];
      ushort4 o;
      o.x = (unsigned short)f2bs(v.x); o.y = (unsigned short)f2bs(v.y);
      o.z = (unsigned short)f2bs(v.z); o.w = (unsigned short)f2bs(v.w);
      reinterpret_cast<ushort4*>(Xb)[i] = o;
    }
  }
}

// ---------------- Kernel 1: QKV projection, bf16 MFMA (R20-proven) ----------------
#define QKV_NBX 18
#define QKV_NBY 197
#define QKV_NWG (QKV_NBX * QKV_NBY)   // 3546

__global__ __launch_bounds__(256, 4) void k_qkv_mfma(
    const bf16* __restrict__ Xb, const bf16* __restrict__ WbT,
    const float* __restrict__ bias,
    bf16* __restrict__ Q, bf16* __restrict__ K, bf16* __restrict__ V) {
  __shared__ __align__(16) short LB[17408];   // 34816 B
  const int tid = threadIdx.x;
  const int wid = tid >> 6, lane = tid & 63;
  const int g = lane >> 4, kl = lane & 15;
  const int wm = wid >> 1, wn = wid & 1;
  const int lin = xcd_swz(blockIdx.x, QKV_NWG);
  const int row0 = (lin / QKV_NBX) * 128;
  const int col0 = (lin % QKV_NBX) * 128;

  auto stage = [&](int k0, int buf) {
#pragma unroll
    for (int r = 0; r < 2; r++) {
      int slotb = r * 256 + wid * 64;         // wave-uniform LDS base
      int slot = slotb + lane;
      int sg = slot >> 7, sm = slot & 127;
      int mm = row0 + sm; if (mm > MROWS - 1) mm = MROWS - 1;
      gload_lds16(Xb + (size_t)mm * DIMC + k0 + sg * 8, &LB[buf * 4096 + (slotb << 3)]);
      gload_lds16(WbT + (size_t)(col0 + sm) * DIMC + k0 + sg * 8,
                  &LB[8192 + buf * 4096 + (slotb << 3)]);
    }
  };

  f32x4 acc[4][4] = {};

  stage(0, 0);
  __syncthreads();

  for (int it = 0; it < 24; it++) {
    const int buf = it & 1;
    if (it < 23) stage((it + 1) * 32, buf ^ 1);

    s16x8 af[4], bf[4];
#pragma unroll
    for (int i = 0; i < 4; i++)
      af[i] = *(const s16x8*)&LB[buf * 4096 + (((g << 7) + wm * 64 + i * 16 + kl) << 3)];
#pragma unroll
    for (int j = 0; j < 4; j++)
      bf[j] = *(const s16x8*)&LB[8192 + buf * 4096 + (((g << 7) + wn * 64 + j * 16 + kl) << 3)];
    __builtin_amdgcn_s_setprio(1);
#pragma unroll
    for (int i = 0; i < 4; i++)
#pragma unroll
      for (int j = 0; j < 4; j++)
        acc[i][j] = __builtin_amdgcn_mfma_f32_16x16x32_bf16(af[i], bf[j], acc[i][j], 0, 0, 0);
    __builtin_amdgcn_s_setprio(0);
    __syncthreads();
  }

  // ---- epilogue: bias + LDS transpose + vectorized coalesced writes ----
#pragma unroll
  for (int i = 0; i < 4; i++)
#pragma unroll
    for (int j = 0; j < 4; j++) {
      int n = wn * 64 + j * 16 + kl;
      float bv = bias[col0 + n];
#pragma unroll
      for (int r = 0; r < 4; r++) {
        int m = wm * 64 + i * 16 + g * 4 + r;
        LB[m * 136 + n] = f2bs(acc[i][j][r] + bv);
      }
    }
  __syncthreads();
#pragma unroll
  for (int cc8 = 0; cc8 < 8; cc8++) {
    int ch = tid + cc8 * 256;
    int m = ch >> 4, cc = ch & 15;
    int M = row0 + m;
    if (M < MROWS) {
      int ncol = col0 + cc * 8;
      int s = ncol / DIMC, rr = ncol % DIMC;
      int h = rr / HD, c = rr % HD;
      int b = M / NTOK, nt = M % NTOK;
      bf16* dst = (s == 0) ? Q : (s == 1) ? K : V;
      *(uint4*)(dst + (((size_t)b * NH + h) * NTOK + nt) * HD + c) =
          *(const uint4*)&LB[m * 136 + cc * 8];
    }
  }
}

// ---------------- Kernel 2a: fused poolK+poolV (stride 2) ----------------
__global__ __launch_bounds__(256) void k_poolKV(
    const bf16* __restrict__ rawK, const bf16* __restrict__ rawV,
    const float* __restrict__ wk, const float* __restrict__ wv,
    const float* __restrict__ gk, const float* __restrict__ bk,
    const float* __restrict__ gv, const float* __restrict__ bv,
    bf16* __restrict__ outK, bf16* __restrict__ outV) {
  const int ntok = 785, ngrp = 197, nb = 64 * ngrp;
  const bool isV = blockIdx.x >= nb;
  const int bid = xcd_swz(isV ? blockIdx.x - nb : blockIdx.x, nb);
  const bf16* raw = isV ? rawV : rawK;
  const float* wgt = isV ? wv : wk;
  const float* gam = isV ? gv : gk;
  const float* bet = isV ? bv : bk;
  bf16* out = isV ? outV : outK;
  const int grp = bid % ngrp;
  const int bh = bid / ngrp;
  const int wid = threadIdx.x >> 6, lane = threadIdx.x & 63;
  const int t = grp * 4 + wid;
  if (t >= ntok) return;
  const bf16* src = raw + (size_t)bh * NTOK * HD;
  const int c2 = lane * 2;

  float v0 = 0.f, v1 = 0.f;
  if (lane < 48) {
    if (t == 0) {
      ushort2 u = *(const ushort2*)(src + c2);
      v0 = s2f((short)u.x); v1 = s2f((short)u.y);
    } else {
      int oy = (t - 1) / 28, ox = (t - 1) % 28;
#pragma unroll
      for (int dy = 0; dy < 3; dy++) {
        int iy = oy * 2 + dy - 1;
        if (iy < 0 || iy >= HH) continue;
#pragma unroll
        for (int dx = 0; dx < 3; dx++) {
          int ix = ox * 2 + dx - 1;
          if (ix < 0 || ix >= WW) continue;
          ushort2 u = *(const ushort2*)(src + (size_t)(1 + iy * WW + ix) * HD + c2);
          float2 w = *(const float2*)(wgt + (dy * 3 + dx) * HD + c2);
          v0 += s2f((short)u.x) * w.x;
          v1 += s2f((short)u.y) * w.y;
        }
      }
    }
  }
  float s = v0 + v1;
  float s2 = v0 * v0 + v1 * v1;
#pragma unroll
  for (int o = 32; o > 0; o >>= 1) {
    s += __shfl_xor(s, o);
    s2 += __shfl_xor(s2, o);
  }
  float mean = s * (1.f / 96.f);
  float var = s2 * (1.f / 96.f) - mean * mean;
  float rstd = rsqrtf(var + 1e-5f);

  if (lane < 48) {
    float2 gm = *(const float2*)(gam + c2);
    float2 bt = *(const float2*)(bet + c2);
    ushort2 o2;
    o2.x = (unsigned short)f2bs((v0 - mean) * rstd * gm.x + bt.x);
    o2.y = (unsigned short)f2bs((v1 - mean) * rstd * gm.y + bt.y);
    *(ushort2*)(out + ((size_t)bh * ntok + t) * HD + c2) = o2;
  }
}

// ---------------- Kernel 2b: poolQ (stride 1) ----------------
__global__ __launch_bounds__(256) void k_poolQ(
    const bf16* __restrict__ raw, const float* __restrict__ wgt,
    const float* __restrict__ gam, const float* __restrict__ bet,
    bf16* __restrict__ out) {
  const int ntok = NTOK, ngrp = 785;
  const int bid = xcd_swz(blockIdx.x, 64 * ngrp);
  const int grp = bid % ngrp;
  const int bh = bid / ngrp;
  const int wid = threadIdx.x >> 6, lane = threadIdx.x & 63;
  const int t = grp * 4 + wid;
  if (t >= ntok) return;
  const bf16* src = raw + (size_t)bh * NTOK * HD;
  const int c2 = lane * 2;

  float v0 = 0.f, v1 = 0.f;
  if (lane < 48) {
    if (t == 0) {
      ushort2 u = *(const ushort2*)(src + c2);
      v0 = s2f((short)u.x); v1 = s2f((short)u.y);
    } else {
      int oy = (t - 1) / WW, ox = (t - 1) % WW;
#pragma unroll
      for (int dy = 0; dy < 3; dy++) {
        int iy = oy + dy - 1;
        if (iy < 0 || iy >= HH) continue;
#pragma unroll
        for (int dx = 0; dx < 3; dx++) {
          int ix = ox + dx - 1;
          if (ix < 0 || ix >= WW) continue;
          ushort2 u = *(const ushort2*)(src + (size_t)(1 + iy * WW + ix) * HD + c2);
          float2 w = *(const float2*)(wgt + (dy * 3 + dx) * HD + c2);
          v0 += s2f((short)u.x) * w.x;
          v1 += s2f((short)u.y) * w.y;
        }
      }
    }
  }
  float s = v0 + v1;
  float s2 = v0 * v0 + v1 * v1;
#pragma unroll
  for (int o = 32; o > 0; o >>= 1) {
    s += __shfl_xor(s, o);
    s2 += __shfl_xor(s2, o);
  }
  float mean = s * (1.f / 96.f);
  float var = s2 * (1.f / 96.f) - mean * mean;
  float rstd = rsqrtf(var + 1e-5f);

  if (lane < 48) {
    float2 gm = *(const float2*)(gam + c2);
    float2 bt = *(const float2*)(bet + c2);
    ushort2 o2;
    o2.x = (unsigned short)f2bs((v0 - mean) * rstd * gm.x + bt.x);
    o2.y = (unsigned short)f2bs((v1 - mean) * rstd * gm.y + bt.y);
    *(ushort2*)(out + ((size_t)bh * ntok + t) * HD + c2) = o2;
  }
}

// ---------------- Kernel 3: MFMA flash attention v9 (v7 + T14 async-STAGE split) ----------------
#define KS_OFF 0
#define VS_OFF 8192
#define RHT_OFF 14528
#define RWT_OFF 16432
#define PS_OFF 18336

__global__ __launch_bounds__(256, 4) void k_attn(
    const bf16* __restrict__ Qp, const bf16* __restrict__ Kp,
    const bf16* __restrict__ Vp, const bf16* __restrict__ BrelG,
    float* __restrict__ out) {
  __shared__ __align__(16) short LB[20384];

  const int bid = blockIdx.x;
  const int swz = (bid & 7) * 400 + (bid >> 3);
  const int bh = swz / 50, qt = swz % 50;
  const int qbase = qt * 64;
  const int tid = threadIdx.x, wid = tid >> 6, lane = tid & 63;
  const int g = lane >> 4, kl = lane & 15;
  const int bb = bh >> 3, hh = bh & 7;
  const float scale = 0.10206207261596575f;

  const bf16* Qbh = Qp + (size_t)bh * NTOK * HD;
  const bf16* Kbh = Kp + (size_t)bh * NKEY * HD;
  const bf16* Vbh = Vp + (size_t)bh * NKEY * HD;

  // ---- Q fragments direct from global ----
  s16x8 qf[3];
  {
    int qg = qbase + wid * 16 + kl; if (qg > NTOK - 1) qg = NTOK - 1;
    const bf16* qptr = Qbh + (size_t)qg * HD;
#pragma unroll
    for (int f = 0; f < 3; f++)
      qf[f] = *(const s16x8*)(qptr + f * 32 + g * 8);
  }

  // ---- fused rel tables: S = Q(64x96) · Brel^T(224x96), gather -> RHT/RWT ----
  {
    short* SfH = &LB[0];          // [64][112]
    short* SfW = &LB[7168];       // [64][112]  (non-overlapping, dead until stage)
    f32x4 accH[7], accW[7];
#pragma unroll
    for (int cf = 0; cf < 7; cf++) {
      accH[cf] = (f32x4){0.f, 0.f, 0.f, 0.f};
      accW[cf] = (f32x4){0.f, 0.f, 0.f, 0.f};
    }
#pragma unroll
    for (int cf = 0; cf < 7; cf++) {
#pragma unroll
      for (int kb = 0; kb < 3; kb++) {
        s16x8 bh_ = *(const s16x8*)((const short*)BrelG + (cf * 16 + kl) * 96 + kb * 32 + g * 8);
        s16x8 bw_ = *(const s16x8*)((const short*)BrelG + (112 + cf * 16 + kl) * 96 + kb * 32 + g * 8);
        accH[cf] = __builtin_amdgcn_mfma_f32_16x16x32_bf16(qf[kb], bh_, accH[cf], 0, 0, 0);
        accW[cf] = __builtin_amdgcn_mfma_f32_16x16x32_bf16(qf[kb], bw_, accW[cf], 0, 0, 0);
      }
    }
#pragma unroll
    for (int cf = 0; cf < 7; cf++)
#pragma unroll
      for (int r = 0; r < 4; r++) {
        int row = wid * 16 + g * 4 + r;
        SfH[row * 112 + cf * 16 + kl] = f2bs(accH[cf][r]);
        SfW[row * 112 + cf * 16 + kl] = f2bs(accW[cf][r]);
      }
    __syncthreads();
    for (int i = tid; i < 1792; i += 256) {
      int ql = i / 28, j = i % 28;
      int qg = qbase + ql; if (qg > NTOK - 1) qg = NTOK - 1;
      int qy, qx;
      if (qg < 1) { qy = 0; qx = 0; } else { qy = (qg - 1) / WW; qx = (qg - 1) % WW; }
      int ih = qy - 2 * j + 54; ih = ih < 0 ? 0 : (ih > 110 ? 110 : ih);
      int iw = qx - 2 * j + 54; iw = iw < 0 ? 0 : (iw > 110 ? 110 : iw);
      LB[RHT_OFF + j * 68 + ql] = SfH[ql * 112 + ih];
      LB[RWT_OFF + j * 68 + ql] = SfW[ql * 112 + iw];
    }
    __syncthreads();
  }

  // ---- all-ones bf16 B-fragment for the row-sum MFMA ----
  s16x8 ones;
#pragma unroll
  for (int e = 0; e < 8; e++) ones[e] = (short)0x3F80;

  // ---- staging descriptors (chunk0: all threads; chunk1: tid<128) ----
  int kd0, vd0, go0, cs0, kd1, vd1, go1, cs1;
  {
    int kk = tid / 12, ch = tid % 12;
    kd0 = kk * 128 + ((ch ^ (kk & 7)) << 3);
    vd0 = (ch >> 1) * 528 + kk * 16 + ((ch & 1) << 3);
    go0 = kk * 96 + ch * 8;
    cs0 = (kk > 16) ? (kk - 16) * 96 : 0;
    int idx = 256 + tid;
    kk = idx / 12; ch = idx % 12;
    kd1 = kk * 128 + ((ch ^ (kk & 7)) << 3);
    vd1 = (ch >> 1) * 528 + kk * 16 + ((ch & 1) << 3);
    go1 = kk * 96 + ch * 8;
    cs1 = (kk > 16) ? (kk - 16) * 96 : 0;
  }

  // prologue: full stage of tile 0 into buf 0
  {
    uint4 ku = *(const uint4*)((const short*)Kbh + go0);
    uint4 vu = *(const uint4*)((const short*)Vbh + go0);
    *(uint4*)&LB[KS_OFF + kd0] = ku;
    *(uint4*)&LB[VS_OFF + vd0] = vu;
    go0 += 32 * 96;
    if (tid < 128) {
      uint4 ku1 = *(const uint4*)((const short*)Kbh + go1);
      uint4 vu1 = *(const uint4*)((const short*)Vbh + go1);
      *(uint4*)&LB[KS_OFF + kd1] = ku1;
      *(uint4*)&LB[VS_OFF + vd1] = vu1;
      go1 += 32 * 96;
    }
  }
  __syncthreads();

  f32x4 o[7];   // o[0..5]: output cblks; o[6]: row-sum (softmax denominator)
#pragma unroll
  for (int cb = 0; cb < 7; cb++) o[cb] = (f32x4){0.f, 0.f, 0.f, 0.f};

  // incremental rel indices (k0g = t*32+kl; e = k0g-1)
  int kx0 = kl - 1;
  int ky0 = 0;
  int kx1 = (15 + kl) % 28;
  int ky1 = (15 + kl) / 28;
  const int qlb = wid * 16 + g * 4;

  for (int t = 0; t < 25; t++) {
    const int buf = t & 1;

    // ---- T14 LOAD phase: issue next-tile global loads (writes deferred) ----
    uint4 ku, vu, ku1, vu1;
    if (t < 24) {
      int a0 = go0 - ((t == 23) ? cs0 : 0);   // staged tile index = t+1
      ku = *(const uint4*)((const short*)Kbh + a0);
      vu = *(const uint4*)((const short*)Vbh + a0);
      go0 += 32 * 96;
      if (tid < 128) {
        int a1 = go1 - ((t == 23) ? cs1 : 0);
        ku1 = *(const uint4*)((const short*)Kbh + a1);
        vu1 = *(const uint4*)((const short*)Vbh + a1);
        go1 += 32 * 96;
      }
    }

    // ---- QK^T ----
    const short* ksb = &LB[KS_OFF + buf * 4096];
    f32x4 s0 = (f32x4){0.f, 0.f, 0.f, 0.f};
    f32x4 s1 = (f32x4){0.f, 0.f, 0.f, 0.f};
    __builtin_amdgcn_s_setprio(1);
#pragma unroll
    for (int f = 0; f < 3; f++) {
      int ch = f * 4 + g;
      int r0 = kl, r1 = 16 + kl;
      s16x8 kf0 = *(const s16x8*)&ksb[r0 * 128 + ((ch ^ (r0 & 7)) << 3)];
      s16x8 kf1 = *(const s16x8*)&ksb[r1 * 128 + ((ch ^ (r1 & 7)) << 3)];
      s0 = __builtin_amdgcn_mfma_f32_16x16x32_bf16(qf[f], kf0, s0, 0, 0, 0);
      s1 = __builtin_amdgcn_mfma_f32_16x16x32_bf16(qf[f], kf1, s1, 0, 0, 0);
    }
    __builtin_amdgcn_s_setprio(0);

    // ---- rel gather: 4x ds_read_b64 from transposed tables ----
    const int k0g = t * 32 + kl;
    const int k1g = k0g + 16;
    int kxu0 = kx0 < 0 ? 0 : kx0;
    int kyu1 = ky1 > 27 ? 27 : ky1;
    s16x4 rh0 = *(const s16x4*)&LB[RHT_OFF + ky0 * 68 + qlb];
    s16x4 rw0 = *(const s16x4*)&LB[RWT_OFF + kxu0 * 68 + qlb];
    s16x4 rh1 = *(const s16x4*)&LB[RHT_OFF + kyu1 * 68 + qlb];
    s16x4 rw1 = *(const s16x4*)&LB[RWT_OFF + kx1 * 68 + qlb];

    // ---- logits + NO-MAX softmax: p = exp(lg) directly (bounded logits) ----
    float p0[4], p1[4];
#pragma unroll
    for (int r = 0; r < 4; r++) {
      int qg = qbase + qlb + r;
      float rel0 = (qg > 0 && k0g > 0) ? s2f(rh0[r]) + s2f(rw0[r]) : 0.f;
      float rel1 = (qg > 0) ? s2f(rh1[r]) + s2f(rw1[r]) : 0.f;
      float lg0 = s0[r] * scale + rel0;
      float lg1 = (k1g < NKEY) ? (s1[r] * scale + rel1) : -1e30f;
      p0[r] = __expf(lg0);
      p1[r] = __expf(lg1);        // expf(-1e30) underflows to 0: masked
    }
    kx0 += 4; ky0 += 1; if (kx0 >= 28) { kx0 -= 28; ky0 += 1; }
    kx1 += 4; ky1 += 1; if (kx1 >= 28) { kx1 -= 28; ky1 += 1; }

    // ---- P^T -> LDS [32k][16q]: 2x ds_write_b64; A-frag via 2x tr-read ----
    short* pw = &LB[PS_OFF + wid * 512];
    s16x4 pk0, pk1;
#pragma unroll
    for (int r = 0; r < 4; r++) { pk0[r] = f2bs(p0[r]); pk1[r] = f2bs(p1[r]); }
    *(s16x4*)(pw + kl * 16 + g * 4) = pk0;
    *(s16x4*)(pw + (16 + kl) * 16 + g * 4) = pk1;
    __builtin_amdgcn_sched_barrier(0);
    uint32_t pbase = (uint32_t)(size_t)pw + (uint32_t)(g * 256 + kl * 8);
    s16x4 pt0, pt1;
    asm volatile("ds_read_b64_tr_b16 %0, %1" : "=v"(pt0) : "v"(pbase));
    asm volatile("ds_read_b64_tr_b16 %0, %1 offset:128" : "=v"(pt1) : "v"(pbase));

    // ---- V tr-reads ----
    uint32_t vbase = (uint32_t)(size_t)&LB[VS_OFF + buf * 3168] + (uint32_t)(g * 256 + kl * 8);
    s16x4 tv[12];
#pragma unroll
    for (int cb = 0; cb < 6; cb++) {
      uint32_t va = vbase + cb * 1056;
      asm volatile("ds_read_b64_tr_b16 %0, %1" : "=v"(tv[2 * cb]) : "v"(va));
      asm volatile("ds_read_b64_tr_b16 %0, %1 offset:128" : "=v"(tv[2 * cb + 1]) : "v"(va));
    }
    asm volatile("s_waitcnt lgkmcnt(0)" ::: "memory");
    __builtin_amdgcn_sched_barrier(0);

    s16x8 pa = __builtin_shufflevector(pt0, pt1, 0, 1, 2, 3, 4, 5, 6, 7);
    __builtin_amdgcn_s_setprio(1);
    o[6] = __builtin_amdgcn_mfma_f32_16x16x32_bf16(pa, ones, o[6], 0, 0, 0);
#pragma unroll
    for (int cb = 0; cb < 6; cb++) {
      s16x8 vf = __builtin_shufflevector(tv[2 * cb], tv[2 * cb + 1], 0, 1, 2, 3, 4, 5, 6, 7);
      o[cb] = __builtin_amdgcn_mfma_f32_16x16x32_bf16(pa, vf, o[cb], 0, 0, 0);
    }
    __builtin_amdgcn_s_setprio(0);

    // ---- T14 WRITE phase: deferred LDS writes into buf^1 (HBM latency hidden) ----
    if (t < 24) {
      short* ksb_n = &LB[KS_OFF + (buf ^ 1) * 4096];
      short* vsb_n = &LB[VS_OFF + (buf ^ 1) * 3168];
      *(uint4*)&ksb_n[kd0] = ku;
      *(uint4*)&vsb_n[vd0] = vu;
      if (tid < 128) {
        *(uint4*)&ksb_n[kd1] = ku1;
        *(uint4*)&vsb_n[vd1] = vu1;
      }
    }
    __syncthreads();
  }

  // ---- epilogue: normalize + residual + transposed store ----
  float inv[4];
#pragma unroll
  for (int r = 0; r < 4; r++) inv[r] = 1.f / o[6][r];
#pragma unroll
  for (int cb = 0; cb < 6; cb++) {
#pragma unroll
    for (int r = 0; r < 4; r++) {
      int ql = qlb + r;
      int qg = qbase + ql;
      if (qg < NTOK) {
        int c = cb * 16 + kl;
        float val = o[cb][r] * inv[r] + b2f(Qbh[(size_t)qg * HD + c]);
        out[((size_t)bb * NTOK + qg) * 768 + hh * 96 + c] = val;
      }
    }
  }
}

// ---------------- launch ----------------
extern "C" void kernel_launch(void* const* d_in, const int* in_sizes, int n_in,
                              void* d_out, int out_size, void* d_ws, size_t ws_size,
                              hipStream_t stream) {
  const float* x = (const float*)d_in[0];
  const float* qkv_w = (const float*)d_in[1];
  const float* qkv_b = (const float*)d_in[2];
  const float* pqw = (const float*)d_in[3];
  const float* pkw = (const float*)d_in[4];
  const float* pvw = (const float*)d_in[5];
  const float* nqg = (const float*)d_in[6];
  const float* nqb = (const float*)d_in[7];
  const float* nkg = (const float*)d_in[8];
  const float* nkb = (const float*)d_in[9];
  const float* nvg = (const float*)d_in[10];
  const float* nvb = (const float*)d_in[11];
  const float* relH = (const float*)d_in[12];
  const float* relW = (const float*)d_in[13];

  const size_t SZQ = (size_t)MROWS * DIMC;             // 19,273,728 elems
  const size_t SZK = (size_t)BATCH * NH * NKEY * HD;   //  4,823,040 elems

  bf16* ws = (bf16*)d_ws;
  bf16* Xb   = (bf16*)d_out;
  bf16* rawV = (bf16*)d_out + SZQ;
  bf16* rawQ = ws;
  bf16* rawK = ws + SZQ;
  bf16* WbT  = ws + 2 * SZQ;
  bf16* poolK = ws + 2 * SZQ;
  bf16* poolV = poolK + SZK;
  bf16* poolQ = rawK;                      // aliases rawK (dead after poolKV)
  bf16* Brel = ws + 2 * SZQ + 2 * SZK;     // outside all written regions
  float* out = (float*)d_out;

  k_cvtAll<<<2501, 256, 0, stream>>>(x, Xb, (int)(SZQ / 4), qkv_w, WbT,
                                     relH, relW, Brel);

  k_qkv_mfma<<<QKV_NWG, 256, 0, stream>>>(Xb, WbT, qkv_b, rawQ, rawK, rawV);

  k_poolKV<<<2 * 64 * 197, 256, 0, stream>>>(rawK, rawV, pkw, pvw,
                                             nkg, nkb, nvg, nvb, poolK, poolV);
  k_poolQ<<<64 * 785, 256, 0, stream>>>(rawQ, pqw, nqg, nqb, poolQ);

  k_attn<<<64 * 50, 256, 0, stream>>>(poolQ, poolK, poolV, Brel, out);
}